// Round 5
// baseline (819.635 us; speedup 1.0000x reference)
//
#include <hip/hip_runtime.h>
#include <math.h>

#define NEG_SLOPE   0.2f
#define CONSUME_R   0.1f     // RADIUS*2
#define ACCEL_SCALE 0.01f
#define MAX_VEL     0.1f

#define NBUCK  2048          // fine dst buckets (sortred grid)
#define NC     256           // coarse dst buckets = NBUCK/8
#define TPB    512
#define EPT    16
#define EPB    (TPB*EPT)     // 8192 edges per slice
#define MAXNPB 128
#define SMAX   6912          // max fine-bucket span in LDS (mean 6250)
#define SCAP   1024          // payS capacity per (xcd-slot, fine bucket)
#define NBMAX  1600          // max slices (LDS directory sizing)

typedef float    v2f __attribute__((ext_vector_type(2)));
typedef unsigned v2u __attribute__((ext_vector_type(2)));

__device__ __forceinline__ unsigned bucket_of(unsigned v, unsigned npb, float inv_npb,
                                              unsigned* loc)
{
    unsigned b = (unsigned)((float)v * inv_npb);
    unsigned lo = b * npb;
    if (v < lo)            { --b; lo -= npb; }
    else if (v >= lo + npb){ ++b; lo += npb; }
    *loc = v - lo;
    return b;
}

// bijective chunked XCD swizzle for scat1 (keeps payS slab writes XCD-local)
__device__ __forceinline__ int slice_of(int blk, int NB)
{
    int q = NB >> 3, r = NB & 7;
    int xcd = blk & 7, idx = blk >> 3;
    return (xcd < r ? xcd * (q + 1) : r * (q + 1) + (xcd - r) * q) + idx;
}

// ---------------------------------------------------------------------------
// k_pre: npack[i] = {h0|h1, h2|h3, h4, aS} (h bf16), aD[i] fp32.
// Also zeroes scal[] and the payS cursors.
// ---------------------------------------------------------------------------
__global__ __launch_bounds__(256) void k_pre(
    const float* __restrict__ x, const float* __restrict__ W,
    const float* __restrict__ att_src, const float* __restrict__ att_dst,
    uint4* __restrict__ npack, float* __restrict__ aD,
    int* __restrict__ pcur, float* __restrict__ scal, int n)
{
    int i = blockIdx.x * 256 + threadIdx.x;
    if (i >= n) return;
    if (i < 16) scal[i] = 0.f;
    if (i < 8 * NBUCK) pcur[i] = 0;
    float xr[5];
#pragma unroll
    for (int k = 0; k < 5; ++k) xr[k] = x[(size_t)i * 5 + k];
    float hs[5];
#pragma unroll
    for (int c = 0; c < 5; ++c) {
        float s = 0.f;
#pragma unroll
        for (int k = 0; k < 5; ++k) s += xr[k] * W[k * 5 + c];
        hs[c] = s;
    }
    float a_s = 0.f, a_d = 0.f;
#pragma unroll
    for (int c = 0; c < 5; ++c) { a_s += hs[c] * att_src[c]; a_d += hs[c] * att_dst[c]; }
    aD[i] = a_d;
    unsigned b[5];
#pragma unroll
    for (int c = 0; c < 5; ++c) {   // round-to-nearest-even bf16
        unsigned u = __float_as_uint(hs[c]);
        b[c] = (u + 0x7FFFu + ((u >> 16) & 1u)) >> 16;
    }
    npack[i] = make_uint4(b[0] | (b[1] << 16), b[2] | (b[3] << 16), b[4],
                          __float_as_uint(a_s));
}

// ---------------------------------------------------------------------------
// k_scat1: per slice, LDS-sort edges by COARSE dst bucket (256 bins), dump
// full 8B recs slice-contiguous (1x write amp, block-owned 64KB region).
// rec: key = src | cloc<<18 (cloc = dst - cb*8*npb, 10 bits), ae f32.
// dirC[cb][slice] (u16, 257 rows) = coarse run offsets within slice.
// payS: (xcd-slot, fine src bucket) slabs via global cursor reservation.
// NO hist / scanA / scanB / global payD cursors.
// ---------------------------------------------------------------------------
__global__ __launch_bounds__(TPB) void k_scat1(
    const int* __restrict__ ei, const float* __restrict__ ea,
    const float* __restrict__ We, const float* __restrict__ att_edge,
    unsigned* __restrict__ slabA, float* __restrict__ slabB,
    unsigned short* __restrict__ dirC,
    unsigned short* __restrict__ payS, int* __restrict__ pcur,
    int NB, int nE, unsigned npb, float inv_npb,
    unsigned npbC, float inv_npbC)
{
    __shared__ unsigned srtA[EPB];     // 32 KB keys
    __shared__ float    srtB[EPB];     // 32 KB ae
    __shared__ int cC[NC], cOffL[NC + 1], cS[NBUCK];
    __shared__ int wscn[4];
    int t = threadIdx.x;
    int sl = slice_of(blockIdx.x, NB);
    int xs = blockIdx.x & 7;
    for (int j = t; j < NBUCK; j += TPB) cS[j] = 0;
    if (t < NC) cC[t] = 0;
    __syncthreads();

    float v0 = 0.f, v1 = 0.f;
#pragma unroll
    for (int c = 0; c < 5; ++c) { v0 += We[c] * att_edge[c]; v1 += We[5 + c] * att_edge[c]; }

    int base = sl * EPB;
    unsigned key[EPT], meta[EPT];
    float ae[EPT];

    // pass A: load, classify, count
#pragma unroll
    for (int k = 0; k < EPT; ++k) {
        int e = base + k * TPB + t;
        meta[k] = 0;
        if (e < nE) {
            unsigned s = (unsigned)__builtin_nontemporal_load(ei + e);
            unsigned d = (unsigned)__builtin_nontemporal_load(ei + nE + e);
            v2f at = __builtin_nontemporal_load((const v2f*)ea + e);
            unsigned cloc, sloc;
            unsigned cb = bucket_of(d, npbC, inv_npbC, &cloc);
            unsigned bs = bucket_of(s, npb, inv_npb, &sloc);
            key[k] = s | (cloc << 18);
            ae[k]  = at.x * v0 + at.y * v1;
            bool close = at.x < CONSUME_R;
            bool cell  = (at.y == 1.0f);
            meta[k] = cb | (bs << 8) | (close ? (1u << 19) : 0u)
                         | (cell ? (1u << 20) : 0u) | (1u << 21);
            atomicAdd(&cC[cb], 1);
            if (close || cell) atomicAdd(&cS[bs], 1);
        }
    }
    __syncthreads();

    // exclusive scan of cC[256] (threads 0..255, 4 waves)
    int v = 0, xv = 0;
    if (t < NC) {
        v = cC[t]; xv = v;
#pragma unroll
        for (int off = 1; off < 64; off <<= 1) {
            int y = __shfl_up(xv, off);
            if ((t & 63) >= off) xv += y;
        }
        if ((t & 63) == 63) wscn[t >> 6] = xv;
    }
    __syncthreads();
    if (t < NC) {
        int add = 0;
        for (int w = 0; w < (t >> 6); ++w) add += wscn[w];
        cOffL[t] = xv - v + add;
        cC[t] = 0;                       // reuse as cursor
        if (t == NC - 1) cOffL[NC] = xv + add;
    }
    // reserve payS runs: cS[j] becomes absolute cursor (base via atomic)
    for (int j = t; j < NBUCK; j += TPB) {
        int c = cS[j];
        cS[j] = c ? atomicAdd(&pcur[xs * NBUCK + j], c) : 0;
    }
    __syncthreads();

    // pass B: place into LDS coarse-sorted; emit payS recs
#pragma unroll
    for (int k = 0; k < EPT; ++k) {
        if (meta[k] & (1u << 21)) {
            unsigned cb = meta[k] & 0xFFu;
            int p = cOffL[cb] + atomicAdd(&cC[cb], 1);
            srtA[p] = key[k];
            srtB[p] = ae[k];
            if (meta[k] & 0x180000u) {
                unsigned bs = (meta[k] >> 8) & 0x7FFu;
                unsigned s = key[k] & 0x3FFFFu;
                unsigned srec = (s - bs * npb) | ((meta[k] >> 19) & 1u) << 11
                                              | ((meta[k] >> 20) & 1u) << 12;
                int p2 = atomicAdd(&cS[bs], 1);
                if (p2 < SCAP)
                    payS[((size_t)xs * NBUCK + bs) * SCAP + p2] = (unsigned short)srec;
            }
        }
    }
    __syncthreads();

    // dump: fully coalesced, block-owned contiguous region (1x write amp)
    unsigned* gA = slabA + (size_t)sl * EPB;
    float*    gB = slabB + (size_t)sl * EPB;
#pragma unroll
    for (int j = t; j < EPB; j += TPB) {
        __builtin_nontemporal_store(srtA[j], gA + j);
        __builtin_nontemporal_store(srtB[j], gB + j);
    }
    // directory (257 rows, transposed: row cb contiguous over slices)
    if (t <= NC) dirC[(size_t)t * NB + sl] = (unsigned short)cOffL[t];
}

// ---------------------------------------------------------------------------
// k_sortred: per FINE bucket. Siblings of one coarse bucket are mapped to the
// SAME XCD (B&7 == cb&7, adjacent launch order) so the cb slab region is
// HBM-fetched once and L2-served 8x. Walk coarse runs, filter fine==f,
// counting-sort into LDS, atomic-free segmented reduce, fused finalize.
// ---------------------------------------------------------------------------
__global__ __launch_bounds__(1024) void k_sortred(
    const unsigned* __restrict__ slabA, const float* __restrict__ slabB,
    const unsigned short* __restrict__ dirC,
    const unsigned short* __restrict__ payS, const int* __restrict__ pcur,
    const uint4* __restrict__ npack, const float* __restrict__ aD,
    const float* __restrict__ x,
    const float* __restrict__ gat_bias, const float* __restrict__ W1,
    const float* __restrict__ b1, const float* __restrict__ W2,
    const float* __restrict__ b2,
    float* __restrict__ out, float* __restrict__ scal,
    int NB, int n, int npb, float inv_npb)
{
    __shared__ unsigned srt[SMAX * 2];          // 55.3 KB sorted recs
    __shared__ unsigned short dOf[NBMAX], dEn[NBMAX];   // 6.4 KB directory
    __shared__ float accf[MAXNPB * 6];
    __shared__ float aDl[MAXNPB];
    __shared__ int cntL[MAXNPB], offL[MAXNPB], cnts[MAXNPB];
    __shared__ int spanS;
    __shared__ float sm[16][5];

    int B = blockIdx.x, t = threadIdx.x;
    int xcd = B & 7, idx = B >> 3;
    int cb = xcd + 8 * (idx >> 3);      // coarse bucket (siblings share XCD)
    int f  = idx & 7;                   // fine-in-coarse
    int b  = cb * 8 + f;                // fine bucket
    int first = b * npb;
    int nodes = n - first; if (nodes > npb) nodes = npb; if (nodes < 0) nodes = 0;

    for (int j = t; j < npb; j += 1024) { cntL[j] = 0; cnts[j] = 0; }
    for (int j = t; j < npb * 6; j += 1024) accf[j] = 0.f;
    for (int j = t; j < nodes; j += 1024) aDl[j] = aD[first + j];
    for (int j = t; j < NB; j += 1024) {
        dOf[j] = dirC[(size_t)cb * NB + j];
        dEn[j] = dirC[(size_t)(cb + 1) * NB + j];
    }
    __syncthreads();

    int grp = t >> 4, l16 = t & 15;     // 64 groups of 16 lanes

    // count walk over coarse runs (filter fine == f)
    for (int sl = grp; sl < NB; sl += 64) {
        int st = dOf[sl], en = dEn[sl];
        const unsigned* pA = slabA + (size_t)sl * EPB;
        for (int r = st + l16; r < en; r += 16) {
            unsigned cloc = pA[r] >> 18;
            unsigned dloc;
            unsigned fl = bucket_of(cloc, npb, inv_npb, &dloc);
            if (fl == (unsigned)f) atomicAdd(&cntL[dloc], 1);
        }
    }
    __syncthreads();
    // wave-0 parallel exclusive scan of cntL[0..npb); span total
    if (t < 64) {
        int i0 = 2 * t, i1 = 2 * t + 1;
        int a0 = (i0 < npb) ? cntL[i0] : 0;
        int a1 = (i1 < npb) ? cntL[i1] : 0;
        int v = a0 + a1;
        int xv = v;
#pragma unroll
        for (int off = 1; off < 64; off <<= 1) {
            int y = __shfl_up(xv, off);
            if (t >= off) xv += y;
        }
        int ex = xv - v;
        if (i0 < npb) { offL[i0] = ex;      cntL[i0] = 0; }
        if (i1 < npb) { offL[i1] = ex + a0; cntL[i1] = 0; }
        if (t == 63) spanS = xv;
    }
    __syncthreads();

    if (spanS <= SMAX) {
        // place walk
        for (int sl = grp; sl < NB; sl += 64) {
            int st = dOf[sl], en = dEn[sl];
            const unsigned* pA = slabA + (size_t)sl * EPB;
            const float*    pB = slabB + (size_t)sl * EPB;
            for (int r = st + l16; r < en; r += 16) {
                unsigned key = pA[r];
                unsigned cloc = key >> 18;
                unsigned dloc;
                unsigned fl = bucket_of(cloc, npb, inv_npb, &dloc);
                if (fl == (unsigned)f) {
                    float aev = pB[r];
                    int p = offL[dloc] + atomicAdd(&cntL[dloc], 1);
                    srt[2 * p] = key & 0x3FFFFu;
                    srt[2 * p + 1] = __float_as_uint(aev);
                }
            }
        }
        __syncthreads();
        // segmented reduce, one node per 16-lane group (atomic-free)
        for (int nd = grp; nd < nodes; nd += 64) {
            int s = offL[nd], e = s + cntL[nd];
            float s0 = 0.f, s1 = 0.f, s2 = 0.f, s3 = 0.f, s4 = 0.f, s5 = 0.f;
            for (int j = s + l16; j < e; j += 16) {
                unsigned w0 = srt[2 * j];
                float aev = __uint_as_float(srt[2 * j + 1]);
                uint4 hp = npack[w0];
                float z = __uint_as_float(hp.w) + aev + aDl[nd];
                float l = z > 0.f ? z : NEG_SLOPE * z;
                float ev = __expf(l);
                s0 += ev * __uint_as_float(hp.x << 16);
                s1 += ev * __uint_as_float(hp.x & 0xFFFF0000u);
                s2 += ev * __uint_as_float(hp.y << 16);
                s3 += ev * __uint_as_float(hp.y & 0xFFFF0000u);
                s4 += ev * __uint_as_float(hp.z << 16);
                s5 += ev;
            }
#pragma unroll
            for (int m = 1; m < 16; m <<= 1) {
                s0 += __shfl_xor(s0, m);
                s1 += __shfl_xor(s1, m);
                s2 += __shfl_xor(s2, m);
                s3 += __shfl_xor(s3, m);
                s4 += __shfl_xor(s4, m);
                s5 += __shfl_xor(s5, m);
            }
            if (l16 == 0) {
                float* a = &accf[nd * 6];
                a[0] += s0; a[1] += s1; a[2] += s2; a[3] += s3; a[4] += s4; a[5] += s5;
            }
        }
    } else {
        // overflow fallback (statistically never): direct atomic accumulate
        for (int sl = grp; sl < NB; sl += 64) {
            int st = dOf[sl], en = dEn[sl];
            const unsigned* pA = slabA + (size_t)sl * EPB;
            const float*    pB = slabB + (size_t)sl * EPB;
            for (int r = st + l16; r < en; r += 16) {
                unsigned key = pA[r];
                unsigned cloc = key >> 18;
                unsigned dloc;
                unsigned fl = bucket_of(cloc, npb, inv_npb, &dloc);
                if (fl == (unsigned)f) {
                    uint4 hp = npack[key & 0x3FFFFu];
                    float z = __uint_as_float(hp.w) + pB[r] + aDl[dloc];
                    float l = z > 0.f ? z : NEG_SLOPE * z;
                    float ev = __expf(l);
                    float* a = &accf[dloc * 6];
                    atomicAdd(a + 0, ev * __uint_as_float(hp.x << 16));
                    atomicAdd(a + 1, ev * __uint_as_float(hp.x & 0xFFFF0000u));
                    atomicAdd(a + 2, ev * __uint_as_float(hp.y << 16));
                    atomicAdd(a + 3, ev * __uint_as_float(hp.y & 0xFFFF0000u));
                    atomicAdd(a + 4, ev * __uint_as_float(hp.z << 16));
                    atomicAdd(a + 5, ev);
                }
            }
        }
    }

    // payS: 8 contiguous runs (one per xcd-slot), lengths from final cursors
    {
        int xsg = t >> 7, l128 = t & 127;
        int len = pcur[xsg * NBUCK + b];
        if (len > SCAP) len = SCAP;
        const unsigned short* run = payS + ((size_t)xsg * NBUCK + b) * SCAP;
        for (int j = l128; j < len; j += 128) {
            unsigned sr = run[j];
            int add = (int)((sr >> 11) & 1u) | (int)(((sr >> 12) & 1u) << 16);
            atomicAdd(&cnts[sr & 0x3FFu], add);
        }
    }
    __syncthreads();

    // fused finalize
    float part[5] = {0.f, 0.f, 0.f, 0.f, 0.f};
    if (t < nodes) {
        int i = first + t;
        const float* a = &accf[t * 6];
        float inv = 1.0f / fmaxf(a[5], 1e-16f);
        float h[5];
#pragma unroll
        for (int c = 0; c < 5; ++c) h[c] = a[c] * inv + gat_bias[c];
        float tt[5];
#pragma unroll
        for (int c = 0; c < 5; ++c) {
            float s = b1[c];
#pragma unroll
            for (int k = 0; k < 5; ++k) s += h[k] * W1[k * 5 + c];
            tt[c] = fmaxf(s, 0.f);
        }
        float u0 = b2[0], u1 = b2[1];
#pragma unroll
        for (int k = 0; k < 5; ++k) { u0 += tt[k] * W2[k * 2]; u1 += tt[k] * W2[k * 2 + 1]; }
        u0 = fmaxf(u0, 0.f) * 2.f - 1.f;
        u1 = fmaxf(u1, 0.f) * 2.f - 1.f;

        float px = x[(size_t)i * 5],     py = x[(size_t)i * 5 + 1];
        float vx = x[(size_t)i * 5 + 2], vy = x[(size_t)i * 5 + 3];
        float ty = x[(size_t)i * 5 + 4];
        float mask = (ty == 1.0f) ? 1.0f : 0.0f;
        float nvx = fminf(fmaxf(vx + u0 * ACCEL_SCALE * mask, -MAX_VEL), MAX_VEL);
        float nvy = fminf(fmaxf(vy + u1 * ACCEL_SCALE * mask, -MAX_VEL), MAX_VEL);
        float npx = px + nvx, npy = py + nvy;

        out[(size_t)i * 5]     = npx;
        out[(size_t)i * 5 + 1] = npy;
        out[(size_t)i * 5 + 2] = nvx;
        out[(size_t)i * 5 + 3] = nvy;
        out[(size_t)i * 5 + 4] = ty;

        part[0] = fabsf(nvx);
        part[1] = fabsf(nvy);
        float bc = 0.f;
        if (fabsf(npx) > 1.0f) bc += logf(fabsf(npx) + 1e-6f);
        if (fabsf(npy) > 1.0f) bc += logf(fabsf(npy) + 1e-6f);
        part[2] = bc;
        int c = cnts[t];
        part[3] = (ty == 0.0f && (c & 0xffff) >= 3) ? 1.f : 0.f;
        part[4] = (ty == 1.0f && (c >> 16) < 1) ? 1.f : 0.f;
    }

#pragma unroll
    for (int q = 0; q < 5; ++q)
#pragma unroll
        for (int off = 32; off > 0; off >>= 1)
            part[q] += __shfl_down(part[q], off);
    int lane = t & 63, wid = t >> 6;
    if (lane == 0)
#pragma unroll
        for (int q = 0; q < 5; ++q) sm[wid][q] = part[q];
    __syncthreads();
    if (t == 0) {
#pragma unroll
        for (int q = 0; q < 5; ++q) {
            float s = 0.f;
#pragma unroll
            for (int w = 0; w < 16; ++w) s += sm[w][q];
            unsafeAtomicAdd(scal + q, s);
        }
    }
}

__global__ void k_tail(const float* __restrict__ scal, float* __restrict__ out, int n)
{
    if (threadIdx.x == 0 && blockIdx.x == 0) {
        size_t base = (size_t)n * 5;
        float invn = 1.0f / (float)n;
        out[base + 0] = scal[0] * invn;
        out[base + 1] = scal[1] * invn;
        out[base + 2] = scal[2];
        out[base + 3] = scal[3];
        out[base + 4] = scal[4];
    }
}

// ------------------- fallback (round-1 atomic path) ------------------------
__global__ __launch_bounds__(256) void k_node_pre_fb(
    const float* __restrict__ x, const float* __restrict__ W,
    const float* __restrict__ att_src, const float* __restrict__ att_dst,
    float* __restrict__ npack, int n)
{
    int i = blockIdx.x * 256 + threadIdx.x;
    if (i >= n) return;
    float xr[5];
#pragma unroll
    for (int k = 0; k < 5; ++k) xr[k] = x[(size_t)i * 5 + k];
    float hs[5];
#pragma unroll
    for (int c = 0; c < 5; ++c) {
        float s = 0.f;
#pragma unroll
        for (int k = 0; k < 5; ++k) s += xr[k] * W[k * 5 + c];
        hs[c] = s;
    }
    float a_s = 0.f, a_d = 0.f;
#pragma unroll
    for (int c = 0; c < 5; ++c) { a_s += hs[c] * att_src[c]; a_d += hs[c] * att_dst[c]; }
    *(float4*)(npack + (size_t)i * 8)     = make_float4(hs[0], hs[1], hs[2], hs[3]);
    *(float4*)(npack + (size_t)i * 8 + 4) = make_float4(hs[4], a_s, a_d, 0.f);
}

__global__ __launch_bounds__(256) void k_edge_fb(
    const int* __restrict__ ei, const float* __restrict__ ea,
    const float* __restrict__ We, const float* __restrict__ att_edge,
    const float* __restrict__ npack, float* __restrict__ acc,
    int* __restrict__ cnt, int nE)
{
    int e = blockIdx.x * 256 + threadIdx.x;
    if (e >= nE) return;
    float v0 = 0.f, v1 = 0.f;
#pragma unroll
    for (int c = 0; c < 5; ++c) { v0 += We[c] * att_edge[c]; v1 += We[5 + c] * att_edge[c]; }
    int s = ei[e];
    int d = ei[nE + e];
    float2 at = *(const float2*)(ea + (size_t)e * 2);
    const float4 p0 = *(const float4*)(npack + (size_t)s * 8);
    const float2 p1 = *(const float2*)(npack + (size_t)s * 8 + 4);
    float a_dst_d = npack[(size_t)d * 8 + 6];
    float z = p1.y + a_dst_d + (at.x * v0 + at.y * v1);
    float l = z > 0.f ? z : NEG_SLOPE * z;
    float ev = __expf(l);
    float* ad = acc + (size_t)d * 8;
    unsafeAtomicAdd(ad + 0, ev * p0.x);
    unsafeAtomicAdd(ad + 1, ev * p0.y);
    unsafeAtomicAdd(ad + 2, ev * p0.z);
    unsafeAtomicAdd(ad + 3, ev * p0.w);
    unsafeAtomicAdd(ad + 4, ev * p1.x);
    unsafeAtomicAdd(ad + 5, ev);
    int cb = (at.x < CONSUME_R ? 1 : 0) | (at.y == 1.0f ? (1 << 16) : 0);
    if (cb) atomicAdd(cnt + s, cb);
}

__global__ __launch_bounds__(256) void k_final_fb(
    const float* __restrict__ x, const float* __restrict__ acc,
    const int* __restrict__ cnt,
    const float* __restrict__ gat_bias, const float* __restrict__ W1,
    const float* __restrict__ b1, const float* __restrict__ W2,
    const float* __restrict__ b2,
    float* __restrict__ out, float* __restrict__ scal, int n)
{
    int i = blockIdx.x * 256 + threadIdx.x;
    float part[5] = {0.f, 0.f, 0.f, 0.f, 0.f};
    if (i < n) {
        const float* a = acc + (size_t)i * 8;
        float inv = 1.0f / fmaxf(a[5], 1e-16f);
        float h[5];
#pragma unroll
        for (int c = 0; c < 5; ++c) h[c] = a[c] * inv + gat_bias[c];
        float tt[5];
#pragma unroll
        for (int c = 0; c < 5; ++c) {
            float s = b1[c];
#pragma unroll
            for (int k = 0; k < 5; ++k) s += h[k] * W1[k * 5 + c];
            tt[c] = fmaxf(s, 0.f);
        }
        float u0 = b2[0], u1 = b2[1];
#pragma unroll
        for (int k = 0; k < 5; ++k) { u0 += tt[k] * W2[k * 2]; u1 += tt[k] * W2[k * 2 + 1]; }
        u0 = fmaxf(u0, 0.f) * 2.f - 1.f;
        u1 = fmaxf(u1, 0.f) * 2.f - 1.f;
        float px = x[(size_t)i * 5],     py = x[(size_t)i * 5 + 1];
        float vx = x[(size_t)i * 5 + 2], vy = x[(size_t)i * 5 + 3];
        float ty = x[(size_t)i * 5 + 4];
        float mask = (ty == 1.0f) ? 1.0f : 0.0f;
        float nvx = fminf(fmaxf(vx + u0 * ACCEL_SCALE * mask, -MAX_VEL), MAX_VEL);
        float nvy = fminf(fmaxf(vy + u1 * ACCEL_SCALE * mask, -MAX_VEL), MAX_VEL);
        float npx = px + nvx, npy = py + nvy;
        out[(size_t)i * 5]     = npx;
        out[(size_t)i * 5 + 1] = npy;
        out[(size_t)i * 5 + 2] = nvx;
        out[(size_t)i * 5 + 3] = nvy;
        out[(size_t)i * 5 + 4] = ty;
        part[0] = fabsf(nvx);
        part[1] = fabsf(nvy);
        float bc = 0.f;
        if (fabsf(npx) > 1.0f) bc += logf(fabsf(npx) + 1e-6f);
        if (fabsf(npy) > 1.0f) bc += logf(fabsf(npy) + 1e-6f);
        part[2] = bc;
        int c = cnt[i];
        part[3] = (ty == 0.0f && (c & 0xffff) >= 3) ? 1.f : 0.f;
        part[4] = (ty == 1.0f && (c >> 16) < 1) ? 1.f : 0.f;
    }
    __shared__ float sm[4][5];
#pragma unroll
    for (int q = 0; q < 5; ++q)
#pragma unroll
        for (int off = 32; off > 0; off >>= 1)
            part[q] += __shfl_down(part[q], off);
    int lane = threadIdx.x & 63, wid = threadIdx.x >> 6;
    if (lane == 0)
#pragma unroll
        for (int q = 0; q < 5; ++q) sm[wid][q] = part[q];
    __syncthreads();
    if (threadIdx.x == 0) {
#pragma unroll
        for (int q = 0; q < 5; ++q)
            unsafeAtomicAdd(scal + q, sm[0][q] + sm[1][q] + sm[2][q] + sm[3][q]);
    }
}

// ---------------------------------------------------------------------------
extern "C" void kernel_launch(void* const* d_in, const int* in_sizes, int n_in,
                              void* d_out, int out_size, void* d_ws, size_t ws_size,
                              hipStream_t stream)
{
    const float* x        = (const float*)d_in[0];
    const int*   ei       = (const int*)  d_in[1];
    const float* ea       = (const float*)d_in[2];
    const float* W        = (const float*)d_in[3];
    const float* att_src  = (const float*)d_in[4];
    const float* att_dst  = (const float*)d_in[5];
    const float* We       = (const float*)d_in[6];
    const float* att_edge = (const float*)d_in[7];
    const float* gat_bias = (const float*)d_in[8];
    const float* b1       = (const float*)d_in[10];
    const float* W1       = (const float*)d_in[9];
    const float* W2       = (const float*)d_in[11];
    const float* b2       = (const float*)d_in[12];

    int n  = in_sizes[0] / 5;
    int nE = in_sizes[1] / 2;

    int npb = (n + NBUCK - 1) / NBUCK;
    int NB = (nE + EPB - 1) / EPB;
    float inv_npb = 1.0f / (float)npb;
    unsigned npbC = (unsigned)npb * 8u;
    float inv_npbC = 1.0f / (float)npbC;

    size_t o = 0;
    auto alloc = [&](size_t bytes) { size_t r = o; o = (o + bytes + 63) & ~63ULL; return r; };
    size_t off_npack = alloc((size_t)n * 16);
    size_t off_aD    = alloc((size_t)n * 4);
    size_t off_dirC  = alloc((size_t)(NC + 1) * NB * 2);
    size_t off_pcur  = alloc((size_t)8 * NBUCK * 4);
    size_t off_payS  = alloc((size_t)8 * NBUCK * SCAP * 2);
    size_t off_scal  = alloc(64);
    size_t off_slabA = alloc((size_t)NB * EPB * 4);
    size_t off_slabB = alloc((size_t)NB * EPB * 4);
    size_t need = o;

    char* wsb = (char*)d_ws;
    bool ok_shape = (n < (1 << 18)) && (npb <= MAXNPB) && (NB >= 1) && (NB <= NBMAX);
    bool fast = ok_shape && (ws_size >= need);

    if (fast) {
        uint4*          npack = (uint4*)(wsb + off_npack);
        float*          aD    = (float*)(wsb + off_aD);
        unsigned short* dirC  = (unsigned short*)(wsb + off_dirC);
        int*            pcur  = (int*)(wsb + off_pcur);
        unsigned short* payS  = (unsigned short*)(wsb + off_payS);
        float*          scal  = (float*)(wsb + off_scal);
        unsigned*       slabA = (unsigned*)(wsb + off_slabA);
        float*          slabB = (float*)(wsb + off_slabB);

        k_pre<<<(n + 255) / 256, 256, 0, stream>>>(x, W, att_src, att_dst, npack, aD,
                                                   pcur, scal, n);
        k_scat1<<<NB, TPB, 0, stream>>>(ei, ea, We, att_edge, slabA, slabB, dirC,
                                        payS, pcur, NB, nE, (unsigned)npb, inv_npb,
                                        npbC, inv_npbC);
        k_sortred<<<NBUCK, 1024, 0, stream>>>(slabA, slabB, dirC, payS, pcur,
                                              npack, aD, x, gat_bias, W1, b1, W2, b2,
                                              (float*)d_out, scal, NB, n, npb, inv_npb);
        k_tail<<<1, 64, 0, stream>>>(scal, (float*)d_out, n);
    } else {
        float* ws    = (float*)d_ws;
        float* npk   = ws;
        float* acc   = ws + (size_t)n * 8;
        int*   cnt   = (int*)(acc + (size_t)n * 8);
        float* scal  = (float*)(cnt + n);
        size_t zbytes = ((size_t)n * 8 + (size_t)n + 8) * sizeof(float);
        hipMemsetAsync(acc, 0, zbytes, stream);
        k_node_pre_fb<<<(n + 255) / 256, 256, 0, stream>>>(x, W, att_src, att_dst, npk, n);
        k_edge_fb<<<(nE + 255) / 256, 256, 0, stream>>>(ei, ea, We, att_edge, npk,
                                                        acc, cnt, nE);
        k_final_fb<<<(n + 255) / 256, 256, 0, stream>>>(x, acc, cnt, gat_bias, W1, b1,
                                                        W2, b2, (float*)d_out, scal, n);
        k_tail<<<1, 64, 0, stream>>>(scal, (float*)d_out, n);
    }
}

// Round 8
// 753.237 us; speedup vs baseline: 1.0881x; 1.0881x over previous
//
#include <hip/hip_runtime.h>
#include <math.h>

#define NEG_SLOPE   0.2f
#define CONSUME_R   0.1f     // RADIUS*2
#define ACCEL_SCALE 0.01f
#define MAX_VEL     0.1f

#define NBUCK  2048
#define TPB    512
#define EPT    16
#define EPB    (TPB*EPT)     // 8192 edges per slice
#define MAXNPB 128
#define SMAX   6912          // max REAL bucket span held in LDS (mean 6250)
#define SCAP   1024          // payS capacity per (xcd-slot, bucket); mean ~706
#define SENT   0xFFFFFFFFu   // padding sentinel key

typedef float    v2f __attribute__((ext_vector_type(2)));
typedef unsigned v2u __attribute__((ext_vector_type(2)));

__device__ __forceinline__ unsigned bucket_of(unsigned v, unsigned npb, float inv_npb,
                                              unsigned* loc)
{
    unsigned b = (unsigned)((float)v * inv_npb);
    unsigned lo = b * npb;
    if (v < lo)            { --b; lo -= npb; }
    else if (v >= lo + npb){ ++b; lo += npb; }
    *loc = v - lo;
    return b;
}

// ---------------------------------------------------------------------------
// k_pre: npack[i] = {h0|h1, h2|h3, h4, aS} (h bf16), aD[i] fp32.
// Also zeroes scal[], pcur[], rtot8[].
// ---------------------------------------------------------------------------
__global__ __launch_bounds__(256) void k_pre(
    const float* __restrict__ x, const float* __restrict__ W,
    const float* __restrict__ att_src, const float* __restrict__ att_dst,
    uint4* __restrict__ npack, float* __restrict__ aD,
    int* __restrict__ pcur, int* __restrict__ rtot8,
    float* __restrict__ scal, int n)
{
    int i = blockIdx.x * 256 + threadIdx.x;
    if (i >= n) return;
    if (i < 16) scal[i] = 0.f;
    if (i < 8 * NBUCK) { pcur[i] = 0; rtot8[i] = 0; }
    float xr[5];
#pragma unroll
    for (int k = 0; k < 5; ++k) xr[k] = x[(size_t)i * 5 + k];
    float hs[5];
#pragma unroll
    for (int c = 0; c < 5; ++c) {
        float s = 0.f;
#pragma unroll
        for (int k = 0; k < 5; ++k) s += xr[k] * W[k * 5 + c];
        hs[c] = s;
    }
    float a_s = 0.f, a_d = 0.f;
#pragma unroll
    for (int c = 0; c < 5; ++c) { a_s += hs[c] * att_src[c]; a_d += hs[c] * att_dst[c]; }
    aD[i] = a_d;
    unsigned b[5];
#pragma unroll
    for (int c = 0; c < 5; ++c) {   // round-to-nearest-even bf16
        unsigned u = __float_as_uint(hs[c]);
        b[c] = (u + 0x7FFFu + ((u >> 16) & 1u)) >> 16;
    }
    npack[i] = make_uint4(b[0] | (b[1] << 16), b[2] | (b[3] << 16), b[4],
                          __float_as_uint(a_s));
}

// ---------------------------------------------------------------------------
// k_cnt: per-slice LDS dst-bucket histogram -> PADDED per-bucket totals via
// atomicAdd into 8 XCD-split copies (rtot8). Replaces hist array + scanA.
// ---------------------------------------------------------------------------
__global__ __launch_bounds__(TPB) void k_cnt(
    const int* __restrict__ dst, int* __restrict__ rtot8,
    int nE, unsigned npb, float inv_npb, int padm)
{
    __shared__ int hd[NBUCK];
    int t = threadIdx.x, blk = blockIdx.x;
    for (int j = t; j < NBUCK; j += TPB) hd[j] = 0;
    __syncthreads();
    int base = blk * EPB;
#pragma unroll 4
    for (int k = 0; k < EPT; ++k) {
        int e = base + k * TPB + t;
        if (e < nE) {
            unsigned loc;
            unsigned bd = bucket_of((unsigned)__builtin_nontemporal_load(dst + e),
                                    npb, inv_npb, &loc);
            atomicAdd(&hd[bd], 1);
        }
    }
    __syncthreads();
    int xs = blk & 7;
    for (int j = t; j < NBUCK; j += TPB) {
        int c = hd[j];
        if (c) atomicAdd(&rtot8[xs * NBUCK + j], (c + padm) & ~padm);
    }
}

// ---------------------------------------------------------------------------
// k_scanB: sum 8 rtot copies, exclusive scan -> bbase[0..NBUCK]; dcur = bbase.
// ---------------------------------------------------------------------------
__global__ __launch_bounds__(1024) void k_scanB(
    const int* __restrict__ rtot8, int* __restrict__ bbase, int* __restrict__ dcur)
{
    __shared__ int wsum[16], wex[16];
    int t = threadIdx.x;
    int a = 0, b2 = 0;
#pragma unroll
    for (int xq = 0; xq < 8; ++xq) {
        a  += rtot8[xq * NBUCK + 2 * t];
        b2 += rtot8[xq * NBUCK + 2 * t + 1];
    }
    int v = a + b2;
    int xv = v;
#pragma unroll
    for (int off = 1; off < 64; off <<= 1) {
        int y = __shfl_up(xv, off);
        if ((t & 63) >= off) xv += y;
    }
    if ((t & 63) == 63) wsum[t >> 6] = xv;
    __syncthreads();
    if (t == 0) { int r = 0; for (int w = 0; w < 16; ++w) { wex[w] = r; r += wsum[w]; } }
    __syncthreads();
    int excl = xv - v + wex[t >> 6];
    bbase[2 * t] = excl;        dcur[2 * t] = excl;
    bbase[2 * t + 1] = excl + a; dcur[2 * t + 1] = excl + a;
    if (t == 1023) bbase[NBUCK] = excl + v;
}

// ---------------------------------------------------------------------------
// k_scatter: one edge pass. payD placement via PADDED global cursor
// reservation (dcur) -> each (slice,bucket) run is 64B-line-exclusive at
// PAD=8, so writeback amp ~1x by construction. Pad slots get SENT dummies.
// ALL payD stores are bounds-clamped to dcap (defense vs fault).
// payS: (xcd-slot, src bucket) slabs via pcur reservation (r3/r5 proven).
// ---------------------------------------------------------------------------
__global__ __launch_bounds__(TPB) void k_scatter(
    const int* __restrict__ ei, const float* __restrict__ ea,
    const float* __restrict__ We, const float* __restrict__ att_edge,
    unsigned* __restrict__ payD, unsigned short* __restrict__ payS,
    int* __restrict__ pcur, int* __restrict__ dcur,
    int nE, unsigned npb, float inv_npb, int padm, long long dcap)
{
    __shared__ int cD[NBUCK], cS[NBUCK];
    __shared__ unsigned dirGl[NBUCK];
    int t = threadIdx.x, blk = blockIdx.x;
    int xs = blk & 7;
    for (int j = t; j < NBUCK; j += TPB) { cD[j] = 0; cS[j] = 0; }
    __syncthreads();

    float v0 = 0.f, v1 = 0.f;
#pragma unroll
    for (int c = 0; c < 5; ++c) { v0 += We[c] * att_edge[c]; v1 += We[5 + c] * att_edge[c]; }

    int base = blk * EPB;
    unsigned key[EPT], bb[EPT];
    float ae[EPT];

    // pass A: stream edges, classify, count
#pragma unroll
    for (int k = 0; k < EPT; ++k) {
        int e = base + k * TPB + t;
        bb[k] = 0;
        if (e < nE) {
            unsigned s = (unsigned)__builtin_nontemporal_load(ei + e);
            unsigned d = (unsigned)__builtin_nontemporal_load(ei + nE + e);
            v2f at = __builtin_nontemporal_load((const v2f*)ea + e);
            unsigned dloc, sloc;
            unsigned bd = bucket_of(d, npb, inv_npb, &dloc);
            unsigned bs = bucket_of(s, npb, inv_npb, &sloc);
            ae[k]  = at.x * v0 + at.y * v1;
            key[k] = s | (dloc << 18);
            bool close = at.x < CONSUME_R;
            bool cell  = (at.y == 1.0f);
            bb[k] = bd | (bs << 11) | (close ? (1u << 22) : 0u)
                       | (cell ? (1u << 23) : 0u) | (1u << 24);
            atomicAdd(&cD[bd], 1);
            if (close || cell) atomicAdd(&cS[bs], 1);
        }
    }
    __syncthreads();

    // reservations: padded payD space (dcur) + payS slabs (pcur)
    for (int j = t; j < NBUCK; j += TPB) {
        int c = cD[j];
        int padc = (c + padm) & ~padm;
        dirGl[j] = padc ? (unsigned)atomicAdd(&dcur[j], padc) : 0u;
        cD[j] = 0;                       // rank cursor
        int f = cS[j];
        cS[j] = f ? atomicAdd(&pcur[xs * NBUCK + j], f) : 0;   // absolute cursor
    }
    __syncthreads();

    // pass B: place payD recs + payS recs (payD bounds-clamped)
#pragma unroll
    for (int k = 0; k < EPT; ++k) {
        if (bb[k] & (1u << 24)) {
            unsigned bd = bb[k] & 0x7FFu;
            int r = atomicAdd(&cD[bd], 1);
            long long pidx = (long long)dirGl[bd] + r;
            if (pidx < dcap) {
                v2u rec; rec.x = key[k]; rec.y = __float_as_uint(ae[k]);
                ((v2u*)payD)[pidx] = rec;
            }
            if (bb[k] & 0xC00000u) {
                unsigned bs = (bb[k] >> 11) & 0x7FFu;
                unsigned sloc = (key[k] & 0x3FFFFu) - bs * npb;
                unsigned srec = sloc | ((bb[k] >> 22) & 1u) << 11 | ((bb[k] >> 23) & 1u) << 12;
                int p2 = atomicAdd(&cS[bs], 1);
                if (p2 < SCAP)
                    payS[((size_t)xs * NBUCK + bs) * SCAP + p2] = (unsigned short)srec;
            }
        }
    }
    __syncthreads();

    // dummy fill: complete each run's padded tail (completes the 64B lines)
    for (int j = t; j < NBUCK; j += TPB) {
        int real = cD[j];
        int padc = (real + padm) & ~padm;
        unsigned b0 = dirGl[j];
        for (int p = real; p < padc; ++p) {
            long long pidx = (long long)b0 + p;
            if (pidx < dcap) {
                v2u rec; rec.x = SENT; rec.y = 0u;
                ((v2u*)payD)[pidx] = rec;
            }
        }
    }
}

// ---------------------------------------------------------------------------
// k_sortred: per fine bucket. Two-pass counting sort of the (padded) bucket
// span into LDS with sentinel skip, then ATOMIC-FREE per-node segmented
// reduction; src-counts from 8 contiguous payS runs; fused MLP/physics.
// ---------------------------------------------------------------------------
__global__ __launch_bounds__(1024) void k_sortred(
    const unsigned* __restrict__ payD, const unsigned short* __restrict__ payS,
    const int* __restrict__ pcur, const int* __restrict__ bbase,
    const uint4* __restrict__ npack, const float* __restrict__ aD,
    const float* __restrict__ x,
    const float* __restrict__ gat_bias, const float* __restrict__ W1,
    const float* __restrict__ b1, const float* __restrict__ W2,
    const float* __restrict__ b2,
    float* __restrict__ out, float* __restrict__ scal,
    int n, int npb, long long dcap)
{
    __shared__ unsigned srt[SMAX * 2];          // 55.3 KB sorted REAL recs
    __shared__ float accf[MAXNPB * 6];
    __shared__ float aDl[MAXNPB];
    __shared__ int cntL[MAXNPB], offL[MAXNPB], cnts[MAXNPB];
    __shared__ int spanS;
    __shared__ float sm[16][5];

    int b = blockIdx.x, t = threadIdx.x;
    int lo = bbase[b], hi = bbase[b + 1];           // PADDED span
    if ((long long)hi > dcap) hi = (int)dcap;       // defensive clamp
    int first = b * npb;
    int nodes = n - first; if (nodes > npb) nodes = npb; if (nodes < 0) nodes = 0;

    for (int j = t; j < npb; j += 1024) { cntL[j] = 0; cnts[j] = 0; }
    for (int j = t; j < npb * 6; j += 1024) accf[j] = 0.f;
    for (int j = t; j < nodes; j += 1024) aDl[j] = aD[first + j];
    __syncthreads();

    int grp = t >> 4, l16 = t & 15;   // 64 groups of 16 lanes

    // pass 1: count per dloc (regular loads -> lines retained for pass 2)
    for (int idx = lo + t; idx < hi; idx += 1024) {
        v2u rec = *((const v2u*)payD + idx);
        if (rec.x != SENT) atomicAdd(&cntL[(rec.x >> 18) & 0x3FFu], 1);
    }
    __syncthreads();
    // wave-0 parallel exclusive scan of cntL[0..npb); real span total
    if (t < 64) {
        int i0 = 2 * t, i1 = 2 * t + 1;
        int a0 = (i0 < npb) ? cntL[i0] : 0;
        int a1 = (i1 < npb) ? cntL[i1] : 0;
        int v = a0 + a1;
        int xv = v;
#pragma unroll
        for (int off = 1; off < 64; off <<= 1) {
            int y = __shfl_up(xv, off);
            if (t >= off) xv += y;
        }
        int ex = xv - v;
        if (i0 < npb) { offL[i0] = ex;      cntL[i0] = 0; }
        if (i1 < npb) { offL[i1] = ex + a0; cntL[i1] = 0; }
        if (t == 63) spanS = xv;
    }
    __syncthreads();

    if (spanS <= SMAX) {
        // pass 2: rank + place into LDS (payD L2-hot from pass 1)
        for (int idx = lo + t; idx < hi; idx += 1024) {
            v2u rec = *((const v2u*)payD + idx);
            if (rec.x != SENT) {
                unsigned dl = (rec.x >> 18) & 0x3FFu;
                int r = atomicAdd(&cntL[dl], 1);
                int p = offL[dl] + r;
                srt[2 * p] = rec.x; srt[2 * p + 1] = rec.y;
            }
        }
        __syncthreads();
        // pass 3: segmented reduce, one node per 16-lane group (atomic-free)
        for (int nd = grp; nd < nodes; nd += 64) {
            int s = offL[nd], e = s + cntL[nd];
            float s0 = 0.f, s1 = 0.f, s2 = 0.f, s3 = 0.f, s4 = 0.f, s5 = 0.f;
            for (int j = s + l16; j < e; j += 16) {
                unsigned w0 = srt[2 * j];
                float aev = __uint_as_float(srt[2 * j + 1]);
                uint4 hp = npack[w0 & 0x3FFFFu];
                float z = __uint_as_float(hp.w) + aev + aDl[nd];
                float l = z > 0.f ? z : NEG_SLOPE * z;
                float ev = __expf(l);
                s0 += ev * __uint_as_float(hp.x << 16);
                s1 += ev * __uint_as_float(hp.x & 0xFFFF0000u);
                s2 += ev * __uint_as_float(hp.y << 16);
                s3 += ev * __uint_as_float(hp.y & 0xFFFF0000u);
                s4 += ev * __uint_as_float(hp.z << 16);
                s5 += ev;
            }
#pragma unroll
            for (int m = 1; m < 16; m <<= 1) {
                s0 += __shfl_xor(s0, m);
                s1 += __shfl_xor(s1, m);
                s2 += __shfl_xor(s2, m);
                s3 += __shfl_xor(s3, m);
                s4 += __shfl_xor(s4, m);
                s5 += __shfl_xor(s5, m);
            }
            if (l16 == 0) {
                float* a = &accf[nd * 6];
                a[0] += s0; a[1] += s1; a[2] += s2; a[3] += s3; a[4] += s4; a[5] += s5;
            }
        }
    } else {
        // overflow fallback (statistically never): direct atomic accumulate
        for (int idx = lo + t; idx < hi; idx += 1024) {
            v2u rec = *((const v2u*)payD + idx);
            if (rec.x == SENT) continue;
            unsigned dl = (rec.x >> 18) & 0x3FFu;
            uint4 hp = npack[rec.x & 0x3FFFFu];
            float z = __uint_as_float(hp.w) + __uint_as_float(rec.y) + aDl[dl];
            float l = z > 0.f ? z : NEG_SLOPE * z;
            float ev = __expf(l);
            float* a = &accf[dl * 6];
            atomicAdd(a + 0, ev * __uint_as_float(hp.x << 16));
            atomicAdd(a + 1, ev * __uint_as_float(hp.x & 0xFFFF0000u));
            atomicAdd(a + 2, ev * __uint_as_float(hp.y << 16));
            atomicAdd(a + 3, ev * __uint_as_float(hp.y & 0xFFFF0000u));
            atomicAdd(a + 4, ev * __uint_as_float(hp.z << 16));
            atomicAdd(a + 5, ev);
        }
    }

    // payS: 8 contiguous runs (one per xcd-slot), lengths from final cursors
    {
        int xsg = t >> 7, l128 = t & 127;
        int len = pcur[xsg * NBUCK + b];
        if (len > SCAP) len = SCAP;
        const unsigned short* run = payS + ((size_t)xsg * NBUCK + b) * SCAP;
        for (int j = l128; j < len; j += 128) {
            unsigned sr = run[j];
            int add = (int)((sr >> 11) & 1u) | (int)(((sr >> 12) & 1u) << 16);
            atomicAdd(&cnts[sr & 0x3FFu], add);
        }
    }
    __syncthreads();

    // fused finalize
    float part[5] = {0.f, 0.f, 0.f, 0.f, 0.f};
    if (t < nodes) {
        int i = first + t;
        const float* a = &accf[t * 6];
        float inv = 1.0f / fmaxf(a[5], 1e-16f);
        float h[5];
#pragma unroll
        for (int c = 0; c < 5; ++c) h[c] = a[c] * inv + gat_bias[c];
        float tt[5];
#pragma unroll
        for (int c = 0; c < 5; ++c) {
            float s = b1[c];
#pragma unroll
            for (int k = 0; k < 5; ++k) s += h[k] * W1[k * 5 + c];
            tt[c] = fmaxf(s, 0.f);
        }
        float u0 = b2[0], u1 = b2[1];
#pragma unroll
        for (int k = 0; k < 5; ++k) { u0 += tt[k] * W2[k * 2]; u1 += tt[k] * W2[k * 2 + 1]; }
        u0 = fmaxf(u0, 0.f) * 2.f - 1.f;
        u1 = fmaxf(u1, 0.f) * 2.f - 1.f;

        float px = x[(size_t)i * 5],     py = x[(size_t)i * 5 + 1];
        float vx = x[(size_t)i * 5 + 2], vy = x[(size_t)i * 5 + 3];
        float ty = x[(size_t)i * 5 + 4];
        float mask = (ty == 1.0f) ? 1.0f : 0.0f;
        float nvx = fminf(fmaxf(vx + u0 * ACCEL_SCALE * mask, -MAX_VEL), MAX_VEL);
        float nvy = fminf(fmaxf(vy + u1 * ACCEL_SCALE * mask, -MAX_VEL), MAX_VEL);
        float npx = px + nvx, npy = py + nvy;

        out[(size_t)i * 5]     = npx;
        out[(size_t)i * 5 + 1] = npy;
        out[(size_t)i * 5 + 2] = nvx;
        out[(size_t)i * 5 + 3] = nvy;
        out[(size_t)i * 5 + 4] = ty;

        part[0] = fabsf(nvx);
        part[1] = fabsf(nvy);
        float bc = 0.f;
        if (fabsf(npx) > 1.0f) bc += logf(fabsf(npx) + 1e-6f);
        if (fabsf(npy) > 1.0f) bc += logf(fabsf(npy) + 1e-6f);
        part[2] = bc;
        int c = cnts[t];
        part[3] = (ty == 0.0f && (c & 0xffff) >= 3) ? 1.f : 0.f;
        part[4] = (ty == 1.0f && (c >> 16) < 1) ? 1.f : 0.f;
    }

#pragma unroll
    for (int q = 0; q < 5; ++q)
#pragma unroll
        for (int off = 32; off > 0; off >>= 1)
            part[q] += __shfl_down(part[q], off);
    int lane = t & 63, wid = t >> 6;
    if (lane == 0)
#pragma unroll
        for (int q = 0; q < 5; ++q) sm[wid][q] = part[q];
    __syncthreads();
    if (t == 0) {
#pragma unroll
        for (int q = 0; q < 5; ++q) {
            float s = 0.f;
#pragma unroll
            for (int w = 0; w < 16; ++w) s += sm[w][q];
            unsafeAtomicAdd(scal + q, s);
        }
    }
}

__global__ void k_tail(const float* __restrict__ scal, float* __restrict__ out, int n)
{
    if (threadIdx.x == 0 && blockIdx.x == 0) {
        size_t base = (size_t)n * 5;
        float invn = 1.0f / (float)n;
        out[base + 0] = scal[0] * invn;
        out[base + 1] = scal[1] * invn;
        out[base + 2] = scal[2];
        out[base + 3] = scal[3];
        out[base + 4] = scal[4];
    }
}

// ------------------- fallback (round-1 atomic path) ------------------------
__global__ __launch_bounds__(256) void k_node_pre_fb(
    const float* __restrict__ x, const float* __restrict__ W,
    const float* __restrict__ att_src, const float* __restrict__ att_dst,
    float* __restrict__ npack, int n)
{
    int i = blockIdx.x * 256 + threadIdx.x;
    if (i >= n) return;
    float xr[5];
#pragma unroll
    for (int k = 0; k < 5; ++k) xr[k] = x[(size_t)i * 5 + k];
    float hs[5];
#pragma unroll
    for (int c = 0; c < 5; ++c) {
        float s = 0.f;
#pragma unroll
        for (int k = 0; k < 5; ++k) s += xr[k] * W[k * 5 + c];
        hs[c] = s;
    }
    float a_s = 0.f, a_d = 0.f;
#pragma unroll
    for (int c = 0; c < 5; ++c) { a_s += hs[c] * att_src[c]; a_d += hs[c] * att_dst[c]; }
    *(float4*)(npack + (size_t)i * 8)     = make_float4(hs[0], hs[1], hs[2], hs[3]);
    *(float4*)(npack + (size_t)i * 8 + 4) = make_float4(hs[4], a_s, a_d, 0.f);
}

__global__ __launch_bounds__(256) void k_edge_fb(
    const int* __restrict__ ei, const float* __restrict__ ea,
    const float* __restrict__ We, const float* __restrict__ att_edge,
    const float* __restrict__ npack, float* __restrict__ acc,
    int* __restrict__ cnt, int nE)
{
    int e = blockIdx.x * 256 + threadIdx.x;
    if (e >= nE) return;
    float v0 = 0.f, v1 = 0.f;
#pragma unroll
    for (int c = 0; c < 5; ++c) { v0 += We[c] * att_edge[c]; v1 += We[5 + c] * att_edge[c]; }
    int s = ei[e];
    int d = ei[nE + e];
    float2 at = *(const float2*)(ea + (size_t)e * 2);
    const float4 p0 = *(const float4*)(npack + (size_t)s * 8);
    const float2 p1 = *(const float2*)(npack + (size_t)s * 8 + 4);
    float a_dst_d = npack[(size_t)d * 8 + 6];
    float z = p1.y + a_dst_d + (at.x * v0 + at.y * v1);
    float l = z > 0.f ? z : NEG_SLOPE * z;
    float ev = __expf(l);
    float* ad = acc + (size_t)d * 8;
    unsafeAtomicAdd(ad + 0, ev * p0.x);
    unsafeAtomicAdd(ad + 1, ev * p0.y);
    unsafeAtomicAdd(ad + 2, ev * p0.z);
    unsafeAtomicAdd(ad + 3, ev * p0.w);
    unsafeAtomicAdd(ad + 4, ev * p1.x);
    unsafeAtomicAdd(ad + 5, ev);
    int cb = (at.x < CONSUME_R ? 1 : 0) | (at.y == 1.0f ? (1 << 16) : 0);
    if (cb) atomicAdd(cnt + s, cb);
}

__global__ __launch_bounds__(256) void k_final_fb(
    const float* __restrict__ x, const float* __restrict__ acc,
    const int* __restrict__ cnt,
    const float* __restrict__ gat_bias, const float* __restrict__ W1,
    const float* __restrict__ b1, const float* __restrict__ W2,
    const float* __restrict__ b2,
    float* __restrict__ out, float* __restrict__ scal, int n)
{
    int i = blockIdx.x * 256 + threadIdx.x;
    float part[5] = {0.f, 0.f, 0.f, 0.f, 0.f};
    if (i < n) {
        const float* a = acc + (size_t)i * 8;
        float inv = 1.0f / fmaxf(a[5], 1e-16f);
        float h[5];
#pragma unroll
        for (int c = 0; c < 5; ++c) h[c] = a[c] * inv + gat_bias[c];
        float tt[5];
#pragma unroll
        for (int c = 0; c < 5; ++c) {
            float s = b1[c];
#pragma unroll
            for (int k = 0; k < 5; ++k) s += h[k] * W1[k * 5 + c];
            tt[c] = fmaxf(s, 0.f);
        }
        float u0 = b2[0], u1 = b2[1];
#pragma unroll
        for (int k = 0; k < 5; ++k) { u0 += tt[k] * W2[k * 2]; u1 += tt[k] * W2[k * 2 + 1]; }
        u0 = fmaxf(u0, 0.f) * 2.f - 1.f;
        u1 = fmaxf(u1, 0.f) * 2.f - 1.f;
        float px = x[(size_t)i * 5],     py = x[(size_t)i * 5 + 1];
        float vx = x[(size_t)i * 5 + 2], vy = x[(size_t)i * 5 + 3];
        float ty = x[(size_t)i * 5 + 4];
        float mask = (ty == 1.0f) ? 1.0f : 0.0f;
        float nvx = fminf(fmaxf(vx + u0 * ACCEL_SCALE * mask, -MAX_VEL), MAX_VEL);
        float nvy = fminf(fmaxf(vy + u1 * ACCEL_SCALE * mask, -MAX_VEL), MAX_VEL);
        float npx = px + nvx, npy = py + nvy;
        out[(size_t)i * 5]     = npx;
        out[(size_t)i * 5 + 1] = npy;
        out[(size_t)i * 5 + 2] = nvx;
        out[(size_t)i * 5 + 3] = nvy;
        out[(size_t)i * 5 + 4] = ty;
        part[0] = fabsf(nvx);
        part[1] = fabsf(nvy);
        float bc = 0.f;
        if (fabsf(npx) > 1.0f) bc += logf(fabsf(npx) + 1e-6f);
        if (fabsf(npy) > 1.0f) bc += logf(fabsf(npy) + 1e-6f);
        part[2] = bc;
        int c = cnt[i];
        part[3] = (ty == 0.0f && (c & 0xffff) >= 3) ? 1.f : 0.f;
        part[4] = (ty == 1.0f && (c >> 16) < 1) ? 1.f : 0.f;
    }
    __shared__ float sm[4][5];
#pragma unroll
    for (int q = 0; q < 5; ++q)
#pragma unroll
        for (int off = 32; off > 0; off >>= 1)
            part[q] += __shfl_down(part[q], off);
    int lane = threadIdx.x & 63, wid = threadIdx.x >> 6;
    if (lane == 0)
#pragma unroll
        for (int q = 0; q < 5; ++q) sm[wid][q] = part[q];
    __syncthreads();
    if (threadIdx.x == 0) {
#pragma unroll
        for (int q = 0; q < 5; ++q)
            unsafeAtomicAdd(scal + q, sm[0][q] + sm[1][q] + sm[2][q] + sm[3][q]);
    }
}

// ---------------------------------------------------------------------------
extern "C" void kernel_launch(void* const* d_in, const int* in_sizes, int n_in,
                              void* d_out, int out_size, void* d_ws, size_t ws_size,
                              hipStream_t stream)
{
    const float* x        = (const float*)d_in[0];
    const int*   ei       = (const int*)  d_in[1];
    const float* ea       = (const float*)d_in[2];
    const float* W        = (const float*)d_in[3];
    const float* att_src  = (const float*)d_in[4];
    const float* att_dst  = (const float*)d_in[5];
    const float* We       = (const float*)d_in[6];
    const float* att_edge = (const float*)d_in[7];
    const float* gat_bias = (const float*)d_in[8];
    const float* b1       = (const float*)d_in[10];
    const float* W1       = (const float*)d_in[9];
    const float* W2       = (const float*)d_in[11];
    const float* b2       = (const float*)d_in[12];

    int n  = in_sizes[0] / 5;
    int nE = in_sizes[1] / 2;

    int npb = (n + NBUCK - 1) / NBUCK;
    int NB = (nE + EPB - 1) / EPB;
    float inv_npb = 1.0f / (float)npb;

    size_t o = 0;
    auto alloc = [&](size_t bytes) { size_t r = o; o = (o + bytes + 63) & ~63ULL; return r; };
    size_t off_npack = alloc((size_t)n * 16);
    size_t off_aD    = alloc((size_t)n * 4);
    size_t off_rtot8 = alloc((size_t)8 * NBUCK * 4);
    size_t off_bbase = alloc((size_t)(NBUCK + 1) * 4);
    size_t off_dcur  = alloc((size_t)NBUCK * 4);
    size_t off_pcur  = alloc((size_t)8 * NBUCK * 4);
    size_t off_payS  = alloc((size_t)8 * NBUCK * SCAP * 2);
    size_t off_scal  = alloc(64);
    size_t off_payD  = alloc(0);          // payD last, size depends on PAD

    // PAD ladder: pick largest pad whose WORST-CASE padded total fits ws.
    int pad = 1;
    for (int p = 8; p >= 2; p >>= 1) {
        size_t cap = (size_t)nE + (size_t)(p - 1) * NB * NBUCK;
        if (off_payD + cap * 8 <= ws_size) { pad = p; break; }
    }
    size_t cap1 = (size_t)nE + (size_t)(pad - 1) * NB * NBUCK;
    size_t need = off_payD + cap1 * 8;

    char* wsb = (char*)d_ws;
    bool ok_shape = (n < (1 << 18)) && (npb <= MAXNPB) && (NB >= 1);
    bool fast = ok_shape && (ws_size >= need);

    if (fast) {
        uint4*          npack = (uint4*)(wsb + off_npack);
        float*          aD    = (float*)(wsb + off_aD);
        int*            rtot8 = (int*)(wsb + off_rtot8);
        int*            bbase = (int*)(wsb + off_bbase);
        int*            dcur  = (int*)(wsb + off_dcur);
        int*            pcur  = (int*)(wsb + off_pcur);
        unsigned short* payS  = (unsigned short*)(wsb + off_payS);
        float*          scal  = (float*)(wsb + off_scal);
        unsigned*       payD  = (unsigned*)(wsb + off_payD);
        int padm = pad - 1;
        long long dcap = (long long)cap1;

        k_pre<<<(n + 255) / 256, 256, 0, stream>>>(x, W, att_src, att_dst, npack, aD,
                                                   pcur, rtot8, scal, n);
        k_cnt<<<NB, TPB, 0, stream>>>(ei + nE, rtot8, nE, (unsigned)npb, inv_npb, padm);
        k_scanB<<<1, 1024, 0, stream>>>(rtot8, bbase, dcur);
        k_scatter<<<NB, TPB, 0, stream>>>(ei, ea, We, att_edge, payD, payS,
                                          pcur, dcur, nE, (unsigned)npb, inv_npb,
                                          padm, dcap);
        k_sortred<<<NBUCK, 1024, 0, stream>>>(payD, payS, pcur, bbase, npack, aD, x,
                                              gat_bias, W1, b1, W2, b2,
                                              (float*)d_out, scal, n, npb, dcap);
        k_tail<<<1, 64, 0, stream>>>(scal, (float*)d_out, n);
    } else {
        float* ws    = (float*)d_ws;
        float* npk   = ws;
        float* acc   = ws + (size_t)n * 8;
        int*   cnt   = (int*)(acc + (size_t)n * 8);
        float* scal  = (float*)(cnt + n);
        size_t zbytes = ((size_t)n * 8 + (size_t)n + 8) * sizeof(float);
        hipMemsetAsync(acc, 0, zbytes, stream);
        k_node_pre_fb<<<(n + 255) / 256, 256, 0, stream>>>(x, W, att_src, att_dst, npk, n);
        k_edge_fb<<<(nE + 255) / 256, 256, 0, stream>>>(ei, ea, We, att_edge, npk,
                                                        acc, cnt, nE);
        k_final_fb<<<(n + 255) / 256, 256, 0, stream>>>(x, acc, cnt, gat_bias, W1, b1,
                                                        W2, b2, (float*)d_out, scal, n);
        k_tail<<<1, 64, 0, stream>>>(scal, (float*)d_out, n);
    }
}